// Round 3
// baseline (345.288 us; speedup 1.0000x reference)
//
#include <hip/hip_runtime.h>
#include <math.h>

typedef float f32x4 __attribute__((ext_vector_type(4)));
typedef short s8v __attribute__((ext_vector_type(8)));

#define LN_EPS 1e-6f

static __device__ __forceinline__ unsigned short f2bf(float f) {
  union { float f; unsigned int u; } v; v.f = f;
  unsigned int r = (v.u + 0x7FFFu + ((v.u >> 16) & 1u)) >> 16;
  return (unsigned short)r;
}
static __device__ __forceinline__ float bf2f(unsigned short b) {
  union { float f; unsigned int u; } v; v.u = ((unsigned int)b) << 16;
  return v.f;
}
static __device__ __forceinline__ float gelu_exact(float x) {
  return 0.5f * x * (1.0f + erff(x * 0.70710678118654752f));
}

// ---------------- prep: fragment-ordered weights (+LN fold) + folded biases --
// frag convention: lane l, elem j <-> k = kstep*32 + (l>>4)*8 + j ; n = n0*16 + (l&15)
// wt0f holds W'[n,c] = w0[n,c]*ln_w[c]. sfold[n]=sum_c w0*ln_w ; tfold[n]=sum_c w0*ln_b + b0.
__global__ void prep_kernel(const float* __restrict__ w0, const float* __restrict__ w1,
                            const float* __restrict__ w2, const float* __restrict__ lnw,
                            const float* __restrict__ lnb, const float* __restrict__ b0,
                            unsigned short* __restrict__ wt0f, unsigned short* __restrict__ w1f,
                            unsigned short* __restrict__ w2f, float* __restrict__ gacc,
                            float* __restrict__ sfold, float* __restrict__ tfold) {
  int idx = blockIdx.x * blockDim.x + threadIdx.x;
  int stride = gridDim.x * blockDim.x;
  const int N0 = 65536, N1 = 16384, N2 = 8192, N3 = 2048, N4 = 256;
  for (int i = idx; i < N0 + N1 + N2 + N3 + N4; i += stride) {
    if (i < N0) {               // w0': (256 out,256 in) -> 16 n0 x 8 kstep
      int j = i & 7, l = (i >> 3) & 63, ks = (i >> 9) & 7, n0 = i >> 12;
      int k = ks * 32 + (l >> 4) * 8 + j;
      wt0f[i] = f2bf(w0[(n0 * 16 + (l & 15)) * 256 + k] * lnw[k]);
    } else if (i < N0 + N1) {   // w1 local half: (128 out, first 128 in)
      int t = i - N0;
      int j = t & 7, l = (t >> 3) & 63, ks = (t >> 9) & 3, n0 = t >> 11;
      w1f[t] = f2bf(w1[(n0 * 16 + (l & 15)) * 256 + ks * 32 + (l >> 4) * 8 + j]);
    } else if (i < N0 + N1 + N2) { // w2: (64 out, 128 in)
      int t = i - N0 - N1;
      int j = t & 7, l = (t >> 3) & 63, ks = (t >> 9) & 3, n0 = t >> 11;
      w2f[t] = f2bf(w2[(n0 * 16 + (l & 15)) * 128 + ks * 32 + (l >> 4) * 8 + j]);
    } else if (i < N0 + N1 + N2 + N3) {
      gacc[i - N0 - N1 - N2] = 0.0f;   // 16 batches x 128 ch
    } else {
      int n = i - N0 - N1 - N2 - N3;
      float s = 0.f, t = 0.f;
      for (int c = 0; c < 256; ++c) {
        float wv = w0[n * 256 + c];
        s += wv * lnw[c];
        t += wv * lnb[c];
      }
      sfold[n] = s;
      tfold[n] = t + b0[n];
    }
  }
}

// ---------------- k1: (dec+enc) -> stats + raw-bf16 GEMM; LN folded in epilogue
// 64 pixels/block, 256 threads (4 waves). GEMM M=64, N=256, K=256.
// Epilogue stages local outputs through LDS for fully-coalesced 16B stores.
__global__ __launch_bounds__(256, 4) void k1_kernel(
    const float* __restrict__ dec, const float* __restrict__ enc,
    const unsigned short* __restrict__ wt0f,
    const float* __restrict__ sfold, const float* __restrict__ tfold,
    unsigned short* __restrict__ yl, float* __restrict__ gacc) {
  __shared__ __align__(16) unsigned char At[64 * 512];   // 32 KiB [p][c] bf16 swz; reused for out
  __shared__ float wred[4][16][8];                       // 2 KiB cross-wave LN partials
  __shared__ float alphaL[64], betaL[64];                // rs, -mu*rs per pixel

  const int tid = threadIdx.x, blk = blockIdx.x;
  const int b = blk >> 8;              // 256 blocks per batch image
  const int hw0 = (blk & 255) << 6;    // 64 pixels
  const int g = tid >> 4, kq = tid & 15;  // g: 8-ch group (0..15), kq: 4-px group (0..15)
  const int lane = tid & 63, w = tid >> 6, l15 = lane & 15, lg = lane >> 4;

  // ---- pass A: x = dec + enc -> raw bf16 At tile; f32 sums in regs ----------
  f32x4 sum = {0.f, 0.f, 0.f, 0.f}, sq = {0.f, 0.f, 0.f, 0.f};
  const long base = (long)(b * 256) * 16384 + hw0 + (kq << 2);
#pragma unroll
  for (int it = 0; it < 2; ++it) {
    f32x4 xv[8];
#pragma unroll
    for (int s = 0; s < 8; ++s) {
      const int c = it * 128 + g * 8 + s;
      f32x4 d = *(const f32x4*)(dec + base + (long)c * 16384);
      f32x4 e = *(const f32x4*)(enc + base + (long)c * 16384);
      f32x4 x = d + e;
      xv[s] = x;
      sum += x;
      sq += x * x;
    }
#pragma unroll
    for (int px = 0; px < 4; ++px) {
      const int p = (kq << 2) + px;
      s8v hv;
#pragma unroll
      for (int s = 0; s < 8; ++s) hv[s] = (short)f2bf(xv[s][px]);
      const int byte = (p * 512 + it * 256 + g * 16) ^ ((p & 7) << 4);
      *(s8v*)(&At[byte]) = hv;
    }
  }

  // ---- LN stats: shfl over g-bits within wave, then cross-wave via LDS ------
#pragma unroll
  for (int q = 0; q < 4; ++q) {
    sum[q] += __shfl_xor(sum[q], 16, 64);
    sq[q] += __shfl_xor(sq[q], 16, 64);
    sum[q] += __shfl_xor(sum[q], 32, 64);
    sq[q] += __shfl_xor(sq[q], 32, 64);
  }
  if (lane < 16) {
#pragma unroll
    for (int q = 0; q < 4; ++q) { wred[w][lane][q] = sum[q]; wred[w][lane][4 + q] = sq[q]; }
  }
  __syncthreads();
  if (tid < 64) {
    const int kk = tid >> 2, q = tid & 3;
    float s = 0.f, s2 = 0.f;
#pragma unroll
    for (int ww = 0; ww < 4; ++ww) { s += wred[ww][kk][q]; s2 += wred[ww][kk][4 + q]; }
    const float mu = s * (1.0f / 256.0f);
    const float var = s2 * (1.0f / 256.0f) - mu * mu;
    const float rs = rsqrtf(var + LN_EPS);
    alphaL[tid] = rs;
    betaL[tid] = -mu * rs;
  }
  __syncthreads();

  // ---- GEMM: wave w -> output cols [64w, 64w+64) ----------------------------
  f32x4 acc[4][4];
#pragma unroll
  for (int mi = 0; mi < 4; ++mi)
#pragma unroll
    for (int ni = 0; ni < 4; ++ni) acc[mi][ni] = (f32x4){0.f, 0.f, 0.f, 0.f};

#pragma unroll
  for (int ks = 0; ks < 8; ++ks) {
    s8v a[4];
#pragma unroll
    for (int mi = 0; mi < 4; ++mi) {
      const int p = mi * 16 + l15;
      const int byte = (p * 512 + ks * 64 + lg * 16) ^ ((p & 7) << 4);
      a[mi] = *(const s8v*)(&At[byte]);
    }
#pragma unroll
    for (int ni = 0; ni < 4; ++ni) {
      const int n0 = w * 4 + ni;
      s8v bfr = *(const s8v*)(wt0f + ((n0 * 8 + ks) * 64 + lane) * 8);
#pragma unroll
      for (int mi = 0; mi < 4; ++mi)
        acc[mi][ni] = __builtin_amdgcn_mfma_f32_16x16x32_bf16(a[mi], bfr, acc[mi][ni], 0, 0, 0);
    }
  }

  __syncthreads();   // all A-reads done; At is now reusable as output staging

  // ---- epilogue: v = rs*acc + (-mu*rs)*s[n] + t[n]; gelu ---------------------
  float sn[4], tn[4];
#pragma unroll
  for (int ni = 0; ni < 4; ++ni) {
    const int n = w * 64 + ni * 16 + l15;
    sn[ni] = sfold[n];
    tn[ni] = tfold[n];
  }

  if (w < 2) {
    // local half: gelu -> bf16 into At as [p][128ch] (256B rows, swz), then wide store
#pragma unroll
    for (int mi = 0; mi < 4; ++mi) {
      const f32x4 al = *(const f32x4*)(&alphaL[mi * 16 + lg * 4]);
      const f32x4 be = *(const f32x4*)(&betaL[mi * 16 + lg * 4]);
#pragma unroll
      for (int r = 0; r < 4; ++r) {
        const int p = mi * 16 + lg * 4 + r;
#pragma unroll
        for (int ni = 0; ni < 4; ++ni) {
          const float v = gelu_exact(fmaf(al[r], acc[mi][ni][r], fmaf(be[r], sn[ni], tn[ni])));
          const int col = w * 64 + ni * 16 + l15;
          const int byte = (p * 256 + col * 2) ^ ((p & 7) << 4);
          *(unsigned short*)(&At[byte]) = f2bf(v);
        }
      }
    }
  } else {
    // global half: gelu, reduce over pixels, atomic into per-batch accumulator
    float ps[4] = {0.f, 0.f, 0.f, 0.f};
#pragma unroll
    for (int mi = 0; mi < 4; ++mi) {
      const f32x4 al = *(const f32x4*)(&alphaL[mi * 16 + lg * 4]);
      const f32x4 be = *(const f32x4*)(&betaL[mi * 16 + lg * 4]);
#pragma unroll
      for (int r = 0; r < 4; ++r) {
#pragma unroll
        for (int ni = 0; ni < 4; ++ni)
          ps[ni] += gelu_exact(fmaf(al[r], acc[mi][ni][r], fmaf(be[r], sn[ni], tn[ni])));
      }
    }
#pragma unroll
    for (int ni = 0; ni < 4; ++ni) {
      float p2 = ps[ni];
      p2 += __shfl_xor(p2, 16, 64);
      p2 += __shfl_xor(p2, 32, 64);
      if (lane < 16) atomicAdd(&gacc[b * 128 + (w - 2) * 64 + ni * 16 + lane], p2);
    }
  }
  __syncthreads();

  // ---- coalesced yl store: 4 iters x (256 threads x 16B) = 16 KiB -----------
  {
    const long rowbase = ((long)b * 16384 + hw0);
#pragma unroll
    for (int q = 0; q < 4; ++q) {
      const int p = q * 16 + (tid >> 4);
      const int colb = (tid & 15) * 16;
      const int byte = (p * 256 + colb) ^ ((p & 7) << 4);
      s8v v = *(const s8v*)(&At[byte]);
      *(s8v*)((char*)yl + (rowbase + p) * 256 + colb) = v;
    }
  }
}

// ---------------- kmid: fold global mean + b1 into per-batch conv1 bias ------
__global__ void kmid_kernel(const float* __restrict__ w1, const float* __restrict__ b1,
                            const float* __restrict__ gacc, float* __restrict__ g1) {
  int b = blockIdx.x, o = threadIdx.x;   // 16 x 128
  float acc = b1[o];
  const float inv = 1.0f / 16384.0f;
  for (int c = 0; c < 128; ++c)
    acc += w1[o * 256 + 128 + c] * (gacc[b * 128 + c] * inv);
  g1[b * 128 + o] = acc;
}

// ---------------- k2: conv1+gelu, conv2+gelu, conv3+sigmoid ------------------
__global__ __launch_bounds__(256, 4) void k2_kernel(
    const unsigned short* __restrict__ yl, const float* __restrict__ g1,
    const float* __restrict__ b2v, const float* __restrict__ w3,
    const float* __restrict__ b3, const unsigned short* __restrict__ w1f,
    const unsigned short* __restrict__ w2f, float* __restrict__ out) {
  __shared__ __align__(16) unsigned char Yt[64 * 256];   // 16 KiB  [p][c<128] bf16 swz
  __shared__ __align__(16) unsigned char Z1[64 * 256];   // 16 KiB
  __shared__ __align__(16) unsigned char Z2[64 * 128];   // 8 KiB
  __shared__ float part3[4][64];
  __shared__ float w3S[64];

  const int tid = threadIdx.x, blk = blockIdx.x;
  const int lane = tid & 63, w = tid >> 6, l15 = lane & 15, lg = lane >> 4;
  const int P0 = blk * 64;
  const int b = blk >> 8;

  if (tid < 64) w3S[tid] = w3[tid];

  // stage yl tile: read linear global rows, write swizzled LDS
#pragma unroll
  for (int q = 0; q < 4; ++q) {
    int p = q * 16 + (tid >> 4);
    int c2 = (tid & 15) * 16;   // byte column, 16-aligned
    s8v v = *(const s8v*)((const char*)yl + (long)(P0 + p) * 256 + c2);
    int byte = (p * 256 + c2) ^ ((p & 7) << 4);
    *(s8v*)(&Yt[byte]) = v;
  }
  __syncthreads();

  // ---- conv1: N=128, wave w -> cols [32w, 32w+32), K=128 --------------------
  f32x4 acc1[4][2];
#pragma unroll
  for (int mi = 0; mi < 4; ++mi)
#pragma unroll
    for (int ni = 0; ni < 2; ++ni) acc1[mi][ni] = (f32x4){0.f, 0.f, 0.f, 0.f};
#pragma unroll
  for (int ks = 0; ks < 4; ++ks) {
    s8v a[4];
#pragma unroll
    for (int mi = 0; mi < 4; ++mi) {
      int p = mi * 16 + l15;
      int byte = (p * 256 + ks * 64 + lg * 16) ^ ((p & 7) << 4);
      a[mi] = *(const s8v*)(&Yt[byte]);
    }
#pragma unroll
    for (int ni = 0; ni < 2; ++ni) {
      int n0 = w * 2 + ni;
      s8v bfr = *(const s8v*)(w1f + ((n0 * 4 + ks) * 64 + lane) * 8);
#pragma unroll
      for (int mi = 0; mi < 4; ++mi)
        acc1[mi][ni] = __builtin_amdgcn_mfma_f32_16x16x32_bf16(a[mi], bfr, acc1[mi][ni], 0, 0, 0);
    }
  }
#pragma unroll
  for (int ni = 0; ni < 2; ++ni) {
    int o = (w * 2 + ni) * 16 + l15;
    float bias = g1[b * 128 + o];
#pragma unroll
    for (int mi = 0; mi < 4; ++mi)
#pragma unroll
      for (int r = 0; r < 4; ++r) {
        int p = mi * 16 + lg * 4 + r;
        float v = gelu_exact(acc1[mi][ni][r] + bias);
        int byte = (p * 256 + o * 2) ^ ((p & 7) << 4);
        *(unsigned short*)(&Z1[byte]) = f2bf(v);
      }
  }
  __syncthreads();

  // ---- conv2: N=64, wave w -> cols [16w, 16w+16), K=128 ---------------------
  f32x4 acc2[4];
#pragma unroll
  for (int mi = 0; mi < 4; ++mi) acc2[mi] = (f32x4){0.f, 0.f, 0.f, 0.f};
#pragma unroll
  for (int ks = 0; ks < 4; ++ks) {
    s8v a[4];
#pragma unroll
    for (int mi = 0; mi < 4; ++mi) {
      int p = mi * 16 + l15;
      int byte = (p * 256 + ks * 64 + lg * 16) ^ ((p & 7) << 4);
      a[mi] = *(const s8v*)(&Z1[byte]);
    }
    s8v bfr = *(const s8v*)(w2f + ((w * 4 + ks) * 64 + lane) * 8);
#pragma unroll
    for (int mi = 0; mi < 4; ++mi)
      acc2[mi] = __builtin_amdgcn_mfma_f32_16x16x32_bf16(a[mi], bfr, acc2[mi], 0, 0, 0);
  }
  {
    int o = w * 16 + l15;
    float bias = b2v[o];
#pragma unroll
    for (int mi = 0; mi < 4; ++mi)
#pragma unroll
      for (int r = 0; r < 4; ++r) {
        int p = mi * 16 + lg * 4 + r;
        float v = gelu_exact(acc2[mi][r] + bias);
        int byte = (p * 128 + o * 2) ^ ((p & 7) << 4);
        *(unsigned short*)(&Z2[byte]) = f2bf(v);
      }
  }
  __syncthreads();

  // ---- conv3 (dot-64) + sigmoid --------------------------------------------
  {
    int p = tid & 63, cg = tid >> 6;
    float dot = 0.f;
#pragma unroll
    for (int half = 0; half < 2; ++half) {
      int byte = (p * 128 + cg * 32 + half * 16) ^ ((p & 7) << 4);
      s8v z = *(const s8v*)(&Z2[byte]);
#pragma unroll
      for (int j = 0; j < 8; ++j)
        dot += bf2f((unsigned short)z[j]) * w3S[cg * 16 + half * 8 + j];
    }
    part3[cg][p] = dot;
  }
  __syncthreads();
  if (tid < 64) {
    float t = part3[0][tid] + part3[1][tid] + part3[2][tid] + part3[3][tid] + b3[0];
    out[P0 + tid] = 1.0f / (1.0f + expf(-t));
  }
}

// ---------------- launch -----------------------------------------------------
extern "C" void kernel_launch(void* const* d_in, const int* in_sizes, int n_in,
                              void* d_out, int out_size, void* d_ws, size_t ws_size,
                              hipStream_t stream) {
  const float* dec = (const float*)d_in[0];
  const float* enc = (const float*)d_in[1];
  const float* lnw = (const float*)d_in[2];
  const float* lnb = (const float*)d_in[3];
  const float* w0  = (const float*)d_in[4];
  const float* b0  = (const float*)d_in[5];
  const float* w1  = (const float*)d_in[6];
  const float* b1  = (const float*)d_in[7];
  const float* w2  = (const float*)d_in[8];
  const float* b2  = (const float*)d_in[9];
  const float* w3  = (const float*)d_in[10];
  const float* b3  = (const float*)d_in[11];

  char* ws = (char*)d_ws;
  unsigned short* yl   = (unsigned short*)ws;                   // 67108864 B
  unsigned short* wt0f = (unsigned short*)(ws + 67108864);      // 131072 B
  unsigned short* w1f  = (unsigned short*)(ws + 67239936);      // 32768 B
  unsigned short* w2f  = (unsigned short*)(ws + 67272704);      // 16384 B
  float* gacc          = (float*)(ws + 67289088);               // 8192 B
  float* g1            = (float*)(ws + 67297280);               // 8192 B
  float* sfold         = (float*)(ws + 67305472);               // 1024 B
  float* tfold         = (float*)(ws + 67306496);               // 1024 B
  // total ws use: 67307520 B (~64.2 MiB)

  prep_kernel<<<128, 256, 0, stream>>>(w0, w1, w2, lnw, lnb, b0, wt0f, w1f, w2f,
                                       gacc, sfold, tfold);
  k1_kernel<<<4096, 256, 0, stream>>>(dec, enc, wt0f, sfold, tfold, yl, gacc);
  kmid_kernel<<<16, 128, 0, stream>>>(w1, b1, gacc, g1);
  k2_kernel<<<4096, 256, 0, stream>>>(yl, g1, b2, w3, b3, w1f, w2f, (float*)d_out);
}

// Round 4
// 207.478 us; speedup vs baseline: 1.6642x; 1.6642x over previous
//
#include <hip/hip_runtime.h>
#include <math.h>

typedef float f32x4 __attribute__((ext_vector_type(4)));
typedef short s8v __attribute__((ext_vector_type(8)));

#define LN_EPS 1e-6f

static __device__ __forceinline__ unsigned short f2bf(float f) {
  union { float f; unsigned int u; } v; v.f = f;
  unsigned int r = (v.u + 0x7FFFu + ((v.u >> 16) & 1u)) >> 16;
  return (unsigned short)r;
}
static __device__ __forceinline__ float bf2f(unsigned short b) {
  union { float f; unsigned int u; } v; v.u = ((unsigned int)b) << 16;
  return v.f;
}
// tanh-form gelu: x * sigmoid(2*sqrt(2/pi)*(x + 0.044715 x^3)); |err| <= ~3e-4
static __device__ __forceinline__ float gelu_fast(float x) {
  float t = x * x;
  float u = x * fmaf(t, 0.07135481283f, 1.5957691216f);
  float e = __expf(-u);
  return __fdividef(x, 1.0f + e);
}

// ---------------- prep: fragment-ordered weights (+LN fold) + folded biases --
// frag convention: lane l, elem j <-> k = kstep*32 + (l>>4)*8 + j ; n = n0*16 + (l&15)
// wt0f holds W'[n,c] = w0[n,c]*ln_w[c]. sfold[n]=sum_c w0*ln_w ; tfold[n]=sum_c w0*ln_b + b0.
__global__ void prep_kernel(const float* __restrict__ w0, const float* __restrict__ w1,
                            const float* __restrict__ w2, const float* __restrict__ lnw,
                            const float* __restrict__ lnb, const float* __restrict__ b0,
                            unsigned short* __restrict__ wt0f, unsigned short* __restrict__ w1f,
                            unsigned short* __restrict__ w2f, float* __restrict__ gacc,
                            float* __restrict__ sfold, float* __restrict__ tfold) {
  int idx = blockIdx.x * blockDim.x + threadIdx.x;
  int stride = gridDim.x * blockDim.x;
  const int N0 = 65536, N1 = 16384, N2 = 8192, N3 = 2048, N4 = 256;
  for (int i = idx; i < N0 + N1 + N2 + N3 + N4; i += stride) {
    if (i < N0) {               // w0': (256 out,256 in) -> 16 n0 x 8 kstep
      int j = i & 7, l = (i >> 3) & 63, ks = (i >> 9) & 7, n0 = i >> 12;
      int k = ks * 32 + (l >> 4) * 8 + j;
      wt0f[i] = f2bf(w0[(n0 * 16 + (l & 15)) * 256 + k] * lnw[k]);
    } else if (i < N0 + N1) {   // w1 local half: (128 out, first 128 in)
      int t = i - N0;
      int j = t & 7, l = (t >> 3) & 63, ks = (t >> 9) & 3, n0 = t >> 11;
      w1f[t] = f2bf(w1[(n0 * 16 + (l & 15)) * 256 + ks * 32 + (l >> 4) * 8 + j]);
    } else if (i < N0 + N1 + N2) { // w2: (64 out, 128 in)
      int t = i - N0 - N1;
      int j = t & 7, l = (t >> 3) & 63, ks = (t >> 9) & 3, n0 = t >> 11;
      w2f[t] = f2bf(w2[(n0 * 16 + (l & 15)) * 128 + ks * 32 + (l >> 4) * 8 + j]);
    } else if (i < N0 + N1 + N2 + N3) {
      gacc[i - N0 - N1 - N2] = 0.0f;   // 16 batches x 128 ch
    } else {
      int n = i - N0 - N1 - N2 - N3;
      float s = 0.f, t = 0.f;
      for (int c = 0; c < 256; ++c) {
        float wv = w0[n * 256 + c];
        s += wv * lnw[c];
        t += wv * lnb[c];
      }
      sfold[n] = s;
      tfold[n] = t + b0[n];
    }
  }
}

// ---------------- k1: (dec+enc) -> stats + raw-bf16 GEMM; LN folded in epilogue
// R1 memory config reproduced exactly: 64 px/block, 4096 blocks, LDS ~41.5 KiB
// (3 blocks/CU), launch_bounds(256,2), direct scalar epilogue stores.
__global__ __launch_bounds__(256, 2) void k1_kernel(
    const float* __restrict__ dec, const float* __restrict__ enc,
    const unsigned short* __restrict__ wt0f,
    const float* __restrict__ sfold, const float* __restrict__ tfold,
    unsigned short* __restrict__ yl, float* __restrict__ gacc) {
  __shared__ __align__(16) unsigned char At[64 * 512];   // 32 KiB [p][c] bf16, XOR-swizzled
  __shared__ float red[16][16][8];                       // 8 KiB partial LN sums (R1 layout)
  __shared__ float alphaL[64], betaL[64];                // rs, -mu*rs per pixel

  const int tid = threadIdx.x, blk = blockIdx.x;
  const int b = blk >> 8;              // 256 blocks per batch image
  const int hw0 = (blk & 255) << 6;    // 64 pixels
  const int g = tid >> 4, kq = tid & 15;  // g: 8-ch group (0..15), kq: 4-px group (0..15)
  const int lane = tid & 63, w = tid >> 6, l15 = lane & 15, lg = lane >> 4;

  // ---- pass A: x = dec + enc -> raw bf16 At tile; f32 partial sums ----------
  f32x4 sum = {0.f, 0.f, 0.f, 0.f}, sq = {0.f, 0.f, 0.f, 0.f};
  const long base = (long)(b * 256) * 16384 + hw0 + (kq << 2);
#pragma unroll
  for (int it = 0; it < 2; ++it) {
    f32x4 xv[8];
#pragma unroll
    for (int s = 0; s < 8; ++s) {
      const int c = it * 128 + g * 8 + s;
      f32x4 d = *(const f32x4*)(dec + base + (long)c * 16384);
      f32x4 e = *(const f32x4*)(enc + base + (long)c * 16384);
      f32x4 x = d + e;
      xv[s] = x;
      sum += x;
      sq += x * x;
    }
#pragma unroll
    for (int px = 0; px < 4; ++px) {
      const int p = (kq << 2) + px;
      s8v hv;
#pragma unroll
      for (int s = 0; s < 8; ++s) hv[s] = (short)f2bf(xv[s][px]);
      const int byte = (p * 512 + it * 256 + g * 16) ^ ((p & 7) << 4);
      *(s8v*)(&At[byte]) = hv;
    }
  }

  // ---- LN stats (R1 pattern): all threads write partials, tid<64 reduce -----
#pragma unroll
  for (int q = 0; q < 4; ++q) { red[g][kq][q] = sum[q]; red[g][kq][4 + q] = sq[q]; }
  __syncthreads();
  if (tid < 64) {
    const int kk = tid >> 2, comp = tid & 3;
    float s = 0.f, s2 = 0.f;
#pragma unroll
    for (int gg = 0; gg < 16; ++gg) { s += red[gg][kk][comp]; s2 += red[gg][kk][4 + comp]; }
    const float mu = s * (1.0f / 256.0f);
    const float var = s2 * (1.0f / 256.0f) - mu * mu;
    const float rs = rsqrtf(var + LN_EPS);
    alphaL[tid] = rs;
    betaL[tid] = -mu * rs;
  }
  __syncthreads();

  // ---- GEMM: wave w -> output cols [64w, 64w+64) ----------------------------
  f32x4 acc[4][4];
#pragma unroll
  for (int mi = 0; mi < 4; ++mi)
#pragma unroll
    for (int ni = 0; ni < 4; ++ni) acc[mi][ni] = (f32x4){0.f, 0.f, 0.f, 0.f};

#pragma unroll
  for (int ks = 0; ks < 8; ++ks) {
    s8v a[4];
#pragma unroll
    for (int mi = 0; mi < 4; ++mi) {
      const int p = mi * 16 + l15;
      const int byte = (p * 512 + ks * 64 + lg * 16) ^ ((p & 7) << 4);
      a[mi] = *(const s8v*)(&At[byte]);
    }
#pragma unroll
    for (int ni = 0; ni < 4; ++ni) {
      const int n0 = w * 4 + ni;
      s8v bfr = *(const s8v*)(wt0f + ((n0 * 8 + ks) * 64 + lane) * 8);
#pragma unroll
      for (int mi = 0; mi < 4; ++mi)
        acc[mi][ni] = __builtin_amdgcn_mfma_f32_16x16x32_bf16(a[mi], bfr, acc[mi][ni], 0, 0, 0);
    }
  }

  // ---- epilogue: v = rs*acc + (-mu*rs)*s[n] + t[n]; fast gelu ----------------
  float sn[4], tn[4];
#pragma unroll
  for (int ni = 0; ni < 4; ++ni) {
    const int n = w * 64 + ni * 16 + l15;
    sn[ni] = sfold[n];
    tn[ni] = tfold[n];
  }

  if (w < 2) {
    // local half: direct scalar stores interleaved with gelu (R1 pattern)
#pragma unroll
    for (int mi = 0; mi < 4; ++mi) {
      const f32x4 al = *(const f32x4*)(&alphaL[mi * 16 + lg * 4]);
      const f32x4 be = *(const f32x4*)(&betaL[mi * 16 + lg * 4]);
#pragma unroll
      for (int r = 0; r < 4; ++r) {
        const int p = mi * 16 + lg * 4 + r;
        const long prow = ((long)b * 16384 + hw0 + p) * 128;
#pragma unroll
        for (int ni = 0; ni < 4; ++ni) {
          const float v = gelu_fast(fmaf(al[r], acc[mi][ni][r], fmaf(be[r], sn[ni], tn[ni])));
          yl[prow + w * 64 + ni * 16 + l15] = f2bf(v);
        }
      }
    }
  } else {
    // global half: gelu, reduce over pixels, atomic into per-batch accumulator
    float ps[4] = {0.f, 0.f, 0.f, 0.f};
#pragma unroll
    for (int mi = 0; mi < 4; ++mi) {
      const f32x4 al = *(const f32x4*)(&alphaL[mi * 16 + lg * 4]);
      const f32x4 be = *(const f32x4*)(&betaL[mi * 16 + lg * 4]);
#pragma unroll
      for (int r = 0; r < 4; ++r) {
#pragma unroll
        for (int ni = 0; ni < 4; ++ni)
          ps[ni] += gelu_fast(fmaf(al[r], acc[mi][ni][r], fmaf(be[r], sn[ni], tn[ni])));
      }
    }
#pragma unroll
    for (int ni = 0; ni < 4; ++ni) {
      float p2 = ps[ni];
      p2 += __shfl_xor(p2, 16, 64);
      p2 += __shfl_xor(p2, 32, 64);
      if (lane < 16) atomicAdd(&gacc[b * 128 + (w - 2) * 64 + ni * 16 + lane], p2);
    }
  }
}

// ---------------- kmid: fold global mean + b1 into per-batch conv1 bias ------
__global__ void kmid_kernel(const float* __restrict__ w1, const float* __restrict__ b1,
                            const float* __restrict__ gacc, float* __restrict__ g1) {
  int b = blockIdx.x, o = threadIdx.x;   // 16 x 128
  float acc = b1[o];
  const float inv = 1.0f / 16384.0f;
  for (int c = 0; c < 128; ++c)
    acc += w1[o * 256 + 128 + c] * (gacc[b * 128 + c] * inv);
  g1[b * 128 + o] = acc;
}

// ---------------- k2: conv1+gelu, conv2+gelu, conv3+sigmoid ------------------
__global__ __launch_bounds__(256, 4) void k2_kernel(
    const unsigned short* __restrict__ yl, const float* __restrict__ g1,
    const float* __restrict__ b2v, const float* __restrict__ w3,
    const float* __restrict__ b3, const unsigned short* __restrict__ w1f,
    const unsigned short* __restrict__ w2f, float* __restrict__ out) {
  __shared__ __align__(16) unsigned char Yt[64 * 256];   // 16 KiB  [p][c<128] bf16 swz
  __shared__ __align__(16) unsigned char Z1[64 * 256];   // 16 KiB
  __shared__ __align__(16) unsigned char Z2[64 * 128];   // 8 KiB
  __shared__ float part3[4][64];
  __shared__ float w3S[64];

  const int tid = threadIdx.x, blk = blockIdx.x;
  const int lane = tid & 63, w = tid >> 6, l15 = lane & 15, lg = lane >> 4;
  const int P0 = blk * 64;
  const int b = blk >> 8;

  if (tid < 64) w3S[tid] = w3[tid];

  // stage yl tile: read linear global rows, write swizzled LDS
#pragma unroll
  for (int q = 0; q < 4; ++q) {
    int p = q * 16 + (tid >> 4);
    int c2 = (tid & 15) * 16;   // byte column, 16-aligned
    s8v v = *(const s8v*)((const char*)yl + (long)(P0 + p) * 256 + c2);
    int byte = (p * 256 + c2) ^ ((p & 7) << 4);
    *(s8v*)(&Yt[byte]) = v;
  }
  __syncthreads();

  // ---- conv1: N=128, wave w -> cols [32w, 32w+32), K=128 --------------------
  f32x4 acc1[4][2];
#pragma unroll
  for (int mi = 0; mi < 4; ++mi)
#pragma unroll
    for (int ni = 0; ni < 2; ++ni) acc1[mi][ni] = (f32x4){0.f, 0.f, 0.f, 0.f};
#pragma unroll
  for (int ks = 0; ks < 4; ++ks) {
    s8v a[4];
#pragma unroll
    for (int mi = 0; mi < 4; ++mi) {
      int p = mi * 16 + l15;
      int byte = (p * 256 + ks * 64 + lg * 16) ^ ((p & 7) << 4);
      a[mi] = *(const s8v*)(&Yt[byte]);
    }
#pragma unroll
    for (int ni = 0; ni < 2; ++ni) {
      int n0 = w * 2 + ni;
      s8v bfr = *(const s8v*)(w1f + ((n0 * 4 + ks) * 64 + lane) * 8);
#pragma unroll
      for (int mi = 0; mi < 4; ++mi)
        acc1[mi][ni] = __builtin_amdgcn_mfma_f32_16x16x32_bf16(a[mi], bfr, acc1[mi][ni], 0, 0, 0);
    }
  }
#pragma unroll
  for (int ni = 0; ni < 2; ++ni) {
    int o = (w * 2 + ni) * 16 + l15;
    float bias = g1[b * 128 + o];
#pragma unroll
    for (int mi = 0; mi < 4; ++mi)
#pragma unroll
      for (int r = 0; r < 4; ++r) {
        int p = mi * 16 + lg * 4 + r;
        float v = gelu_fast(acc1[mi][ni][r] + bias);
        int byte = (p * 256 + o * 2) ^ ((p & 7) << 4);
        *(unsigned short*)(&Z1[byte]) = f2bf(v);
      }
  }
  __syncthreads();

  // ---- conv2: N=64, wave w -> cols [16w, 16w+16), K=128 ---------------------
  f32x4 acc2[4];
#pragma unroll
  for (int mi = 0; mi < 4; ++mi) acc2[mi] = (f32x4){0.f, 0.f, 0.f, 0.f};
#pragma unroll
  for (int ks = 0; ks < 4; ++ks) {
    s8v a[4];
#pragma unroll
    for (int mi = 0; mi < 4; ++mi) {
      int p = mi * 16 + l15;
      int byte = (p * 256 + ks * 64 + lg * 16) ^ ((p & 7) << 4);
      a[mi] = *(const s8v*)(&Z1[byte]);
    }
    s8v bfr = *(const s8v*)(w2f + ((w * 4 + ks) * 64 + lane) * 8);
#pragma unroll
    for (int mi = 0; mi < 4; ++mi)
      acc2[mi] = __builtin_amdgcn_mfma_f32_16x16x32_bf16(a[mi], bfr, acc2[mi], 0, 0, 0);
  }
  {
    int o = w * 16 + l15;
    float bias = b2v[o];
#pragma unroll
    for (int mi = 0; mi < 4; ++mi)
#pragma unroll
      for (int r = 0; r < 4; ++r) {
        int p = mi * 16 + lg * 4 + r;
        float v = gelu_fast(acc2[mi][r] + bias);
        int byte = (p * 128 + o * 2) ^ ((p & 7) << 4);
        *(unsigned short*)(&Z2[byte]) = f2bf(v);
      }
  }
  __syncthreads();

  // ---- conv3 (dot-64) + sigmoid --------------------------------------------
  {
    int p = tid & 63, cg = tid >> 6;
    float dot = 0.f;
#pragma unroll
    for (int half = 0; half < 2; ++half) {
      int byte = (p * 128 + cg * 32 + half * 16) ^ ((p & 7) << 4);
      s8v z = *(const s8v*)(&Z2[byte]);
#pragma unroll
      for (int j = 0; j < 8; ++j)
        dot += bf2f((unsigned short)z[j]) * w3S[cg * 16 + half * 8 + j];
    }
    part3[cg][p] = dot;
  }
  __syncthreads();
  if (tid < 64) {
    float t = part3[0][tid] + part3[1][tid] + part3[2][tid] + part3[3][tid] + b3[0];
    out[P0 + tid] = __fdividef(1.0f, 1.0f + __expf(-t));
  }
}

// ---------------- launch -----------------------------------------------------
extern "C" void kernel_launch(void* const* d_in, const int* in_sizes, int n_in,
                              void* d_out, int out_size, void* d_ws, size_t ws_size,
                              hipStream_t stream) {
  const float* dec = (const float*)d_in[0];
  const float* enc = (const float*)d_in[1];
  const float* lnw = (const float*)d_in[2];
  const float* lnb = (const float*)d_in[3];
  const float* w0  = (const float*)d_in[4];
  const float* b0  = (const float*)d_in[5];
  const float* w1  = (const float*)d_in[6];
  const float* b1  = (const float*)d_in[7];
  const float* w2  = (const float*)d_in[8];
  const float* b2  = (const float*)d_in[9];
  const float* w3  = (const float*)d_in[10];
  const float* b3  = (const float*)d_in[11];

  char* ws = (char*)d_ws;
  unsigned short* yl   = (unsigned short*)ws;                   // 67108864 B
  unsigned short* wt0f = (unsigned short*)(ws + 67108864);      // 131072 B
  unsigned short* w1f  = (unsigned short*)(ws + 67239936);      // 32768 B
  unsigned short* w2f  = (unsigned short*)(ws + 67272704);      // 16384 B
  float* gacc          = (float*)(ws + 67289088);               // 8192 B
  float* g1            = (float*)(ws + 67297280);               // 8192 B
  float* sfold         = (float*)(ws + 67305472);               // 1024 B
  float* tfold         = (float*)(ws + 67306496);               // 1024 B
  // total ws use: 67307520 B (~64.2 MiB)

  prep_kernel<<<128, 256, 0, stream>>>(w0, w1, w2, lnw, lnb, b0, wt0f, w1f, w2f,
                                       gacc, sfold, tfold);
  k1_kernel<<<4096, 256, 0, stream>>>(dec, enc, wt0f, sfold, tfold, yl, gacc);
  kmid_kernel<<<16, 128, 0, stream>>>(w1, b1, gacc, g1);
  k2_kernel<<<4096, 256, 0, stream>>>(yl, g1, b2, w3, b3, w1f, w2f, (float*)d_out);
}